// Round 5
// baseline (522.501 us; speedup 1.0000x reference)
//
#include <hip/hip_runtime.h>
#include <math.h>

// Problem constants
#define L_SEQ 131072
#define NSTATE 256
#define HDIM   256
#define KDIM   512            // 2*NSTATE: re/im interleaved columns
#define LC     128            // scan chunk length
#define NCHUNK (L_SEQ / LC)   // 1024

typedef __bf16 bf16x8 __attribute__((ext_vector_type(8)));
typedef float  f32x4  __attribute__((ext_vector_type(4)));

__device__ __forceinline__ float bf2f(unsigned short u) {
    unsigned int v = (unsigned int)u << 16;
    float f; __builtin_memcpy(&f, &v, 4); return f;
}
__device__ __forceinline__ unsigned short f2bf(float f) {
    unsigned int v; __builtin_memcpy(&v, &f, 4);
    unsigned int lsb = (v >> 16) & 1u;
    v += 0x7fffu + lsb;               // round-to-nearest-even
    return (unsigned short)(v >> 16);
}

__device__ __forceinline__ void gl_lds16(const void* g, void* l) {
    __builtin_amdgcn_global_load_lds(
        (const __attribute__((address_space(1))) void*)g,
        (__attribute__((address_space(3))) void*)l, 16, 0, 0);
}

// ---------------------------------------------------------------------------
// K0: prep — W1 (512x256 bf16, rows 2n=Bre*g, 2n+1=Bim*g), W2 (256x512 bf16,
// cols 2n=Cre, 2n+1=-Cim), Lambda, Lambda^LC.  grid 256 x 256.
// ---------------------------------------------------------------------------
__global__ void prep_kernel(const float* __restrict__ nu_log,
                            const float* __restrict__ theta_log,
                            const float* __restrict__ B_re,
                            const float* __restrict__ B_im,
                            const float* __restrict__ C_re,
                            const float* __restrict__ C_im,
                            const float* __restrict__ gamma_log,
                            unsigned short* __restrict__ W1,
                            unsigned short* __restrict__ W2,
                            float2* __restrict__ Lambda,
                            float2* __restrict__ lamLc) {
    const int bid = blockIdx.x;   // n for W1, h for W2
    const int tid = threadIdx.x;  // h for W1, n for W2
    // W1
    {
        int n = bid, h = tid;
        float g = expf(gamma_log[n]);
        W1[(size_t)(2 * n + 0) * HDIM + h] = f2bf(B_re[(size_t)n * HDIM + h] * g);
        W1[(size_t)(2 * n + 1) * HDIM + h] = f2bf(B_im[(size_t)n * HDIM + h] * g);
    }
    // W2
    {
        int h = bid, n = tid;
        W2[(size_t)h * KDIM + 2 * n + 0] = f2bf(C_re[(size_t)h * NSTATE + n]);
        W2[(size_t)h * KDIM + 2 * n + 1] = f2bf(-C_im[(size_t)h * NSTATE + n]);
    }
    if (bid == 0) {
        int n = tid;
        float a = expf(nu_log[n]);
        float b = expf(theta_log[n]);
        float r = expf(-a);
        Lambda[n] = make_float2(r * cosf(b), r * sinf(b));
        float rl = expf(-a * (float)LC);
        float bl = b * (float)LC;
        lamLc[n] = make_float2(rl * cosf(bl), rl * sinf(bl));
    }
}

// ---------------------------------------------------------------------------
// K0b: cast x fp32 -> bf16 (8 elems/thread)
// ---------------------------------------------------------------------------
__launch_bounds__(256)
__global__ void castx_kernel(const float* __restrict__ x,
                             unsigned short* __restrict__ xb) {
    size_t i = ((size_t)blockIdx.x * 256 + threadIdx.x) * 8;
    float4 a = *(const float4*)(x + i);
    float4 b = *(const float4*)(x + i + 4);
    union { unsigned short s[8]; uint4 v; } u;
    u.s[0] = f2bf(a.x); u.s[1] = f2bf(a.y); u.s[2] = f2bf(a.z); u.s[3] = f2bf(a.w);
    u.s[4] = f2bf(b.x); u.s[5] = f2bf(b.y); u.s[6] = f2bf(b.z); u.s[7] = f2bf(b.w);
    *(uint4*)(xb + i) = u.v;
}

// ---------------------------------------------------------------------------
// MFMA bf16 GEMM, m97 structure + T1 XCD swizzle (verified round 4, 457us).
// Round-5 single change: 2-phase DOUBLE-BUFFERED K-loop (safe form).
//   stage(t+1) into buf (t+1)&1 is issued BEFORE the ds_read+MFMA of tile t
//   (buf t&1), so the global->LDS latency hides under compute.  ONE
//   __syncthreads per K-step; its implicit vmcnt(0)+lgkmcnt(0) drain for
//   EVERY wave guarantees (a) buf (t+1)&1 has fully landed before iteration
//   t+1 reads it, (b) all ds_reads of the buffer stage(t+2) overwrites have
//   completed before any wave issues stage(t+2).  No raw barriers, no LDS
//   swizzle — values and rounding bit-identical to round 4.
// EPI2: out fp32 = acc + D[col]*x[idx]; else: out bf16.
// ---------------------------------------------------------------------------
template <int K, int NT, bool EPI2>
__launch_bounds__(256)
__global__ void gemm_mfma(const unsigned short* __restrict__ A,
                          const unsigned short* __restrict__ B,
                          int ldc,
                          unsigned short* __restrict__ Cb,
                          float* __restrict__ Cf,
                          const float* __restrict__ Dv,
                          const float* __restrict__ x) {
    __shared__ __align__(16) unsigned short As[2][128 * 32];
    __shared__ __align__(16) unsigned short Bs[2][128 * 32];

    const int tid  = threadIdx.x;
    const int wave = tid >> 6;
    const int lane = tid & 63;
    const int quad = lane >> 4;
    const int l16  = lane & 15;
    const int wm   = wave >> 1;   // 0..1
    const int wn   = wave & 1;    // 0..1
    const int srow = lane >> 2;          // 0..15 row within 16-row chunk
    const int scol = (lane & 3) * 8;     // bf16 elem offset within 32-elem row

    // ---- T1: XCD-aware bijective swizzle (nwg = NT*1024, %8 == 0) ----
    const int wg  = blockIdx.y * NT + blockIdx.x;
    const int cpx = (NT * (L_SEQ / 128)) >> 3;   // blocks per XCD chunk
    const int sw  = (wg & 7) * cpx + (wg >> 3);  // bijective
    const int m0  = (sw / NT) * 128;
    const int n0  = (sw % NT) * 128;

    f32x4 acc[4][4] = {};

    constexpr int T = K / 32;

    auto stage = [&](int t) {
        const int cur = t & 1;
        const int kt  = t * 32;
        #pragma unroll
        for (int q = 0; q < 2; ++q) {
            const int rr = (wave * 2 + q) * 16;
            const unsigned short* ga = A + (size_t)(m0 + rr + srow) * K + kt + scol;
            const unsigned short* gb = B + (size_t)(n0 + rr + srow) * K + kt + scol;
            gl_lds16(ga, &As[cur][rr * 32]);
            gl_lds16(gb, &Bs[cur][rr * 32]);
        }
    };

    stage(0);
    __syncthreads();                      // buf 0 landed (full drain)

    #pragma unroll
    for (int t = 0; t < T; ++t) {
        if (t + 1 < T) stage(t + 1);      // prefetch next tile under compute

        const unsigned short* as = &As[t & 1][0];
        const unsigned short* bs = &Bs[t & 1][0];

        bf16x8 af[4], bfr[4];
        #pragma unroll
        for (int i = 0; i < 4; ++i)
            af[i] = *(const bf16x8*)(as + ((size_t)(wm * 64 + i * 16 + l16)) * 32 + quad * 8);
        #pragma unroll
        for (int j = 0; j < 4; ++j)
            bfr[j] = *(const bf16x8*)(bs + ((size_t)(wn * 64 + j * 16 + l16)) * 32 + quad * 8);
        #pragma unroll
        for (int i = 0; i < 4; ++i)
            #pragma unroll
            for (int j = 0; j < 4; ++j)
                acc[i][j] = __builtin_amdgcn_mfma_f32_16x16x32_bf16(af[i], bfr[j], acc[i][j], 0, 0, 0);

        __syncthreads();                  // next tile landed; this buf's reads done
    }

    // epilogue: C/D layout col=lane&15, row=quad*4+reg
    #pragma unroll
    for (int i = 0; i < 4; ++i) {
        const int rowb = m0 + wm * 64 + i * 16 + quad * 4;
        #pragma unroll
        for (int j = 0; j < 4; ++j) {
            const int col = n0 + wn * 64 + j * 16 + l16;
            #pragma unroll
            for (int r = 0; r < 4; ++r) {
                const size_t idx = (size_t)(rowb + r) * ldc + col;
                if (EPI2) {
                    Cf[idx] = fmaf(Dv[col], x[idx], acc[i][j][r]);
                } else {
                    Cb[idx] = f2bf(acc[i][j][r]);
                }
            }
        }
    }
}

// ---------------------------------------------------------------------------
// K2: per-chunk local scan over bf16 Bu (interleaved re/im), carry in fp32
// ---------------------------------------------------------------------------
__launch_bounds__(256)
__global__ void scan1_kernel(const unsigned short* __restrict__ Bu,
                             const float2* __restrict__ Lambda,
                             float2* __restrict__ chunk_local) {
    const int c = blockIdx.x;
    const int n = threadIdx.x;
    const float2 lam = Lambda[n];
    float zr = 0.f, zi = 0.f;
    const unsigned short* p = Bu + (size_t)c * LC * KDIM + 2 * n;
    #pragma unroll 8
    for (int l = 0; l < LC; ++l) {
        unsigned int v = *(const unsigned int*)(p + (size_t)l * KDIM);
        float br = bf2f((unsigned short)(v & 0xffffu));
        float bi = bf2f((unsigned short)(v >> 16));
        float nzr = fmaf(lam.x, zr, fmaf(-lam.y, zi, br));
        float nzi = fmaf(lam.x, zi, fmaf(lam.y, zr, bi));
        zr = nzr; zi = nzi;
    }
    chunk_local[c * NSTATE + n] = make_float2(zr, zi);
}

// ---------------------------------------------------------------------------
// K3: Kogge-Stone parallel scan over the 1024 chunk carries.
// ---------------------------------------------------------------------------
__launch_bounds__(1024)
__global__ void scan2_kernel(const float2* __restrict__ chunk_local,
                             const float2* __restrict__ lamLc,
                             float2* __restrict__ chunk_prefix) {
    __shared__ float2 sbuf[NCHUNK];
    const int n = blockIdx.x;
    const int c = threadIdx.x;
    float2 lam = lamLc[n];          // coefficient for step 1
    float2 b = chunk_local[c * NSTATE + n];
    sbuf[c] = b;
    __syncthreads();
    #pragma unroll
    for (int step = 1; step < NCHUNK; step <<= 1) {
        float2 prev = make_float2(0.f, 0.f);
        if (c >= step) prev = sbuf[c - step];
        __syncthreads();
        if (c >= step) {
            b.x = fmaf(lam.x, prev.x, fmaf(-lam.y, prev.y, b.x));
            b.y = fmaf(lam.x, prev.y, fmaf(lam.y, prev.x, b.y));
        }
        sbuf[c] = b;
        float lr = fmaf(lam.x, lam.x, -lam.y * lam.y);
        float li = 2.f * lam.x * lam.y;
        lam = make_float2(lr, li);
        __syncthreads();
    }
    chunk_prefix[c * NSTATE + n] = b;
}

// ---------------------------------------------------------------------------
// K4: re-scan with true carry-in, write bf16 states in place over Bu
// ---------------------------------------------------------------------------
__launch_bounds__(256)
__global__ void scan3_kernel(unsigned short* __restrict__ Bu,
                             const float2* __restrict__ Lambda,
                             const float2* __restrict__ chunk_prefix) {
    const int c = blockIdx.x;
    const int n = threadIdx.x;
    const float2 lam = Lambda[n];
    float zr = 0.f, zi = 0.f;
    if (c > 0) {
        float2 z0 = chunk_prefix[(c - 1) * NSTATE + n];
        zr = z0.x; zi = z0.y;
    }
    unsigned short* p = Bu + (size_t)c * LC * KDIM + 2 * n;
    #pragma unroll 8
    for (int l = 0; l < LC; ++l) {
        unsigned int v = *(const unsigned int*)(p + (size_t)l * KDIM);
        float br = bf2f((unsigned short)(v & 0xffffu));
        float bi = bf2f((unsigned short)(v >> 16));
        float nzr = fmaf(lam.x, zr, fmaf(-lam.y, zi, br));
        float nzi = fmaf(lam.x, zi, fmaf(lam.y, zr, bi));
        zr = nzr; zi = nzi;
        unsigned int o = (unsigned int)f2bf(nzr) | ((unsigned int)f2bf(nzi) << 16);
        *(unsigned int*)(p + (size_t)l * KDIM) = o;
    }
}

// ---------------------------------------------------------------------------
// Host launch
// ---------------------------------------------------------------------------
extern "C" void kernel_launch(void* const* d_in, const int* in_sizes, int n_in,
                              void* d_out, int out_size, void* d_ws, size_t ws_size,
                              hipStream_t stream) {
    const float* x         = (const float*)d_in[0];
    const float* nu_log    = (const float*)d_in[1];
    const float* theta_log = (const float*)d_in[2];
    const float* B_re      = (const float*)d_in[3];
    const float* B_im      = (const float*)d_in[4];
    const float* C_re      = (const float*)d_in[5];
    const float* C_im      = (const float*)d_in[6];
    const float* Dvec      = (const float*)d_in[7];
    const float* gamma_log = (const float*)d_in[8];
    float* out = (float*)d_out;

    char* ws = (char*)d_ws;
    const size_t BU_BYTES    = (size_t)L_SEQ * KDIM * 2;          // 134 MB bf16
    const size_t XB_BYTES    = (size_t)L_SEQ * HDIM * 2;          // 67 MB bf16
    const size_t W1_BYTES    = (size_t)KDIM * HDIM * 2;           // 256 KB
    const size_t W2_BYTES    = (size_t)HDIM * KDIM * 2;           // 256 KB
    const size_t LAM_BYTES   = (size_t)NSTATE * sizeof(float2);
    const size_t CHUNK_BYTES = (size_t)NCHUNK * NSTATE * sizeof(float2);  // 2 MB

    size_t off = 0;
    unsigned short* Bu  = (unsigned short*)(ws + off); off += BU_BYTES;
    unsigned short* xb  = (unsigned short*)(ws + off); off += XB_BYTES;
    unsigned short* W1  = (unsigned short*)(ws + off); off += W1_BYTES;
    unsigned short* W2  = (unsigned short*)(ws + off); off += W2_BYTES;
    float2* Lambda      = (float2*)(ws + off); off += LAM_BYTES;
    float2* lamLc       = (float2*)(ws + off); off += LAM_BYTES;
    float2* chunk_local = (float2*)(ws + off); off += CHUNK_BYTES;
    float2* chunk_pref  = (float2*)(ws + off); off += CHUNK_BYTES;
    if (ws_size < off) return;

    prep_kernel<<<dim3(256), dim3(256), 0, stream>>>(
        nu_log, theta_log, B_re, B_im, C_re, C_im, gamma_log, W1, W2, Lambda, lamLc);

    castx_kernel<<<dim3((L_SEQ * HDIM) / (256 * 8)), dim3(256), 0, stream>>>(x, xb);

    // GEMM1: (L x 256) * (512 x 256)^T -> Bu (L x 512 bf16, interleaved re/im)
    gemm_mfma<HDIM, KDIM / 128, false>
        <<<dim3(KDIM / 128, L_SEQ / 128), dim3(256), 0, stream>>>(
        xb, W1, KDIM, Bu, nullptr, nullptr, nullptr);

    scan1_kernel<<<dim3(NCHUNK), dim3(NSTATE), 0, stream>>>(Bu, Lambda, chunk_local);
    scan2_kernel<<<dim3(NSTATE), dim3(NCHUNK), 0, stream>>>(chunk_local, lamLc, chunk_pref);
    scan3_kernel<<<dim3(NCHUNK), dim3(NSTATE), 0, stream>>>(Bu, Lambda, chunk_pref);

    // GEMM2: (L x 512) * (256 x 512)^T + D*x -> out (L x 256 fp32)
    gemm_mfma<KDIM, HDIM / 128, true>
        <<<dim3(HDIM / 128, L_SEQ / 128), dim3(256), 0, stream>>>(
        Bu, W2, HDIM, nullptr, out, Dvec, x);
}

// Round 6
// 450.027 us; speedup vs baseline: 1.1610x; 1.1610x over previous
//
#include <hip/hip_runtime.h>
#include <math.h>

// Problem constants
#define L_SEQ 131072
#define NSTATE 256
#define HDIM   256
#define KDIM   512            // 2*NSTATE: re/im interleaved columns
#define LC     128            // scan chunk length
#define NCHUNK (L_SEQ / LC)   // 1024

typedef __bf16 bf16x8 __attribute__((ext_vector_type(8)));
typedef float  f32x4  __attribute__((ext_vector_type(4)));

__device__ __forceinline__ float bf2f(unsigned short u) {
    unsigned int v = (unsigned int)u << 16;
    float f; __builtin_memcpy(&f, &v, 4); return f;
}
__device__ __forceinline__ unsigned short f2bf(float f) {
    unsigned int v; __builtin_memcpy(&v, &f, 4);
    unsigned int lsb = (v >> 16) & 1u;
    v += 0x7fffu + lsb;               // round-to-nearest-even
    return (unsigned short)(v >> 16);
}

__device__ __forceinline__ void gl_lds16(const void* g, void* l) {
    __builtin_amdgcn_global_load_lds(
        (const __attribute__((address_space(1))) void*)g,
        (__attribute__((address_space(3))) void*)l, 16, 0, 0);
}

// ---------------------------------------------------------------------------
// K0: prep — W1 (512x256 bf16, rows 2n=Bre*g, 2n+1=Bim*g), W2 (256x512 bf16,
// cols 2n=Cre, 2n+1=-Cim), Lambda, Lambda^LC.  grid 256 x 256.
// ---------------------------------------------------------------------------
__global__ void prep_kernel(const float* __restrict__ nu_log,
                            const float* __restrict__ theta_log,
                            const float* __restrict__ B_re,
                            const float* __restrict__ B_im,
                            const float* __restrict__ C_re,
                            const float* __restrict__ C_im,
                            const float* __restrict__ gamma_log,
                            unsigned short* __restrict__ W1,
                            unsigned short* __restrict__ W2,
                            float2* __restrict__ Lambda,
                            float2* __restrict__ lamLc) {
    const int bid = blockIdx.x;   // n for W1, h for W2
    const int tid = threadIdx.x;  // h for W1, n for W2
    // W1
    {
        int n = bid, h = tid;
        float g = expf(gamma_log[n]);
        W1[(size_t)(2 * n + 0) * HDIM + h] = f2bf(B_re[(size_t)n * HDIM + h] * g);
        W1[(size_t)(2 * n + 1) * HDIM + h] = f2bf(B_im[(size_t)n * HDIM + h] * g);
    }
    // W2
    {
        int h = bid, n = tid;
        W2[(size_t)h * KDIM + 2 * n + 0] = f2bf(C_re[(size_t)h * NSTATE + n]);
        W2[(size_t)h * KDIM + 2 * n + 1] = f2bf(-C_im[(size_t)h * NSTATE + n]);
    }
    if (bid == 0) {
        int n = tid;
        float a = expf(nu_log[n]);
        float b = expf(theta_log[n]);
        float r = expf(-a);
        Lambda[n] = make_float2(r * cosf(b), r * sinf(b));
        float rl = expf(-a * (float)LC);
        float bl = b * (float)LC;
        lamLc[n] = make_float2(rl * cosf(bl), rl * sinf(bl));
    }
}

// ---------------------------------------------------------------------------
// K0b: cast x fp32 -> bf16 (8 elems/thread)
// ---------------------------------------------------------------------------
__launch_bounds__(256)
__global__ void castx_kernel(const float* __restrict__ x,
                             unsigned short* __restrict__ xb) {
    size_t i = ((size_t)blockIdx.x * 256 + threadIdx.x) * 8;
    float4 a = *(const float4*)(x + i);
    float4 b = *(const float4*)(x + i + 4);
    union { unsigned short s[8]; uint4 v; } u;
    u.s[0] = f2bf(a.x); u.s[1] = f2bf(a.y); u.s[2] = f2bf(a.z); u.s[3] = f2bf(a.w);
    u.s[4] = f2bf(b.x); u.s[5] = f2bf(b.y); u.s[6] = f2bf(b.z); u.s[7] = f2bf(b.w);
    *(uint4*)(xb + i) = u.v;
}

// ---------------------------------------------------------------------------
// MFMA bf16 GEMM, m97 structure + T1 XCD swizzle (verified round 4, 457us).
// Round-6 single change: process TWO BK=32 sub-tiles per sync-pair (BK=64
// per barrier, stored as two stacked 128x32 linear tiles so global_load_lds
// destinations and ds_read patterns are IDENTICAL to the verified kernel).
// Halves the number of vmcnt(0)-drain events (GEMM1 8->4, GEMM2 16->8),
// which is the measured bottleneck (MfmaUtil 12%, HBM 31% — latency-bound).
// No dbuf, no prefetch-before-compute (round-5 showed hipcc serializes
// global_load_lds against ds_read), no LDS layout change, accumulation
// order bit-identical (kt then kt+32 per acc).
// EPI2: out fp32 = acc + D[col]*x[idx]; else: out bf16.
// ---------------------------------------------------------------------------
template <int K, int NT, bool EPI2>
__launch_bounds__(256)
__global__ void gemm_mfma(const unsigned short* __restrict__ A,
                          const unsigned short* __restrict__ B,
                          int ldc,
                          unsigned short* __restrict__ Cb,
                          float* __restrict__ Cf,
                          const float* __restrict__ Dv,
                          const float* __restrict__ x) {
    // four linear 128x32 tiles: A-sub0, A-sub1, B-sub0, B-sub1
    __shared__ __align__(16) unsigned short lds[4 * 4096];

    const int tid  = threadIdx.x;
    const int wave = tid >> 6;
    const int lane = tid & 63;
    const int quad = lane >> 4;
    const int l16  = lane & 15;
    const int wm   = wave >> 1;   // 0..1
    const int wn   = wave & 1;    // 0..1
    const int srow = lane >> 2;          // 0..15 row within 16-row chunk
    const int scol = (lane & 3) * 8;     // bf16 elem offset within 32-elem row

    // ---- T1: XCD-aware bijective swizzle (nwg = NT*1024, %8 == 0) ----
    const int wg  = blockIdx.y * NT + blockIdx.x;
    const int cpx = (NT * (L_SEQ / 128)) >> 3;   // blocks per XCD chunk
    const int sw  = (wg & 7) * cpx + (wg >> 3);  // bijective
    const int m0  = (sw / NT) * 128;
    const int n0  = (sw % NT) * 128;

    f32x4 acc[4][4] = {};

    for (int kt = 0; kt < K; kt += 64) {
        #pragma unroll
        for (int q = 0; q < 2; ++q) {
            const int rr = (wave * 2 + q) * 16;
            const unsigned short* ga = A + (size_t)(m0 + rr + srow) * K + kt + scol;
            const unsigned short* gb = B + (size_t)(n0 + rr + srow) * K + kt + scol;
            gl_lds16(ga,      lds         + rr * 32);   // A sub0 (k 0..31)
            gl_lds16(ga + 32, lds + 4096  + rr * 32);   // A sub1 (k 32..63)
            gl_lds16(gb,      lds + 8192  + rr * 32);   // B sub0
            gl_lds16(gb + 32, lds + 12288 + rr * 32);   // B sub1
        }
        __syncthreads();

        #pragma unroll
        for (int s = 0; s < 2; ++s) {
            const unsigned short* as = lds + s * 4096;
            const unsigned short* bs = lds + 8192 + s * 4096;

            bf16x8 af[4], bfr[4];
            #pragma unroll
            for (int i = 0; i < 4; ++i)
                af[i] = *(const bf16x8*)(as + ((size_t)(wm * 64 + i * 16 + l16)) * 32 + quad * 8);
            #pragma unroll
            for (int j = 0; j < 4; ++j)
                bfr[j] = *(const bf16x8*)(bs + ((size_t)(wn * 64 + j * 16 + l16)) * 32 + quad * 8);
            #pragma unroll
            for (int i = 0; i < 4; ++i)
                #pragma unroll
                for (int j = 0; j < 4; ++j)
                    acc[i][j] = __builtin_amdgcn_mfma_f32_16x16x32_bf16(af[i], bfr[j], acc[i][j], 0, 0, 0);
        }
        __syncthreads();
    }

    // epilogue: C/D layout col=lane&15, row=quad*4+reg
    #pragma unroll
    for (int i = 0; i < 4; ++i) {
        const int rowb = m0 + wm * 64 + i * 16 + quad * 4;
        #pragma unroll
        for (int j = 0; j < 4; ++j) {
            const int col = n0 + wn * 64 + j * 16 + l16;
            #pragma unroll
            for (int r = 0; r < 4; ++r) {
                const size_t idx = (size_t)(rowb + r) * ldc + col;
                if (EPI2) {
                    Cf[idx] = fmaf(Dv[col], x[idx], acc[i][j][r]);
                } else {
                    Cb[idx] = f2bf(acc[i][j][r]);
                }
            }
        }
    }
}

// ---------------------------------------------------------------------------
// K2: per-chunk local scan over bf16 Bu (interleaved re/im), carry in fp32
// ---------------------------------------------------------------------------
__launch_bounds__(256)
__global__ void scan1_kernel(const unsigned short* __restrict__ Bu,
                             const float2* __restrict__ Lambda,
                             float2* __restrict__ chunk_local) {
    const int c = blockIdx.x;
    const int n = threadIdx.x;
    const float2 lam = Lambda[n];
    float zr = 0.f, zi = 0.f;
    const unsigned short* p = Bu + (size_t)c * LC * KDIM + 2 * n;
    #pragma unroll 8
    for (int l = 0; l < LC; ++l) {
        unsigned int v = *(const unsigned int*)(p + (size_t)l * KDIM);
        float br = bf2f((unsigned short)(v & 0xffffu));
        float bi = bf2f((unsigned short)(v >> 16));
        float nzr = fmaf(lam.x, zr, fmaf(-lam.y, zi, br));
        float nzi = fmaf(lam.x, zi, fmaf(lam.y, zr, bi));
        zr = nzr; zi = nzi;
    }
    chunk_local[c * NSTATE + n] = make_float2(zr, zi);
}

// ---------------------------------------------------------------------------
// K3: Kogge-Stone parallel scan over the 1024 chunk carries.
// ---------------------------------------------------------------------------
__launch_bounds__(1024)
__global__ void scan2_kernel(const float2* __restrict__ chunk_local,
                             const float2* __restrict__ lamLc,
                             float2* __restrict__ chunk_prefix) {
    __shared__ float2 sbuf[NCHUNK];
    const int n = blockIdx.x;
    const int c = threadIdx.x;
    float2 lam = lamLc[n];          // coefficient for step 1
    float2 b = chunk_local[c * NSTATE + n];
    sbuf[c] = b;
    __syncthreads();
    #pragma unroll
    for (int step = 1; step < NCHUNK; step <<= 1) {
        float2 prev = make_float2(0.f, 0.f);
        if (c >= step) prev = sbuf[c - step];
        __syncthreads();
        if (c >= step) {
            b.x = fmaf(lam.x, prev.x, fmaf(-lam.y, prev.y, b.x));
            b.y = fmaf(lam.x, prev.y, fmaf(lam.y, prev.x, b.y));
        }
        sbuf[c] = b;
        float lr = fmaf(lam.x, lam.x, -lam.y * lam.y);
        float li = 2.f * lam.x * lam.y;
        lam = make_float2(lr, li);
        __syncthreads();
    }
    chunk_prefix[c * NSTATE + n] = b;
}

// ---------------------------------------------------------------------------
// K4: re-scan with true carry-in, write bf16 states in place over Bu
// ---------------------------------------------------------------------------
__launch_bounds__(256)
__global__ void scan3_kernel(unsigned short* __restrict__ Bu,
                             const float2* __restrict__ Lambda,
                             const float2* __restrict__ chunk_prefix) {
    const int c = blockIdx.x;
    const int n = threadIdx.x;
    const float2 lam = Lambda[n];
    float zr = 0.f, zi = 0.f;
    if (c > 0) {
        float2 z0 = chunk_prefix[(c - 1) * NSTATE + n];
        zr = z0.x; zi = z0.y;
    }
    unsigned short* p = Bu + (size_t)c * LC * KDIM + 2 * n;
    #pragma unroll 8
    for (int l = 0; l < LC; ++l) {
        unsigned int v = *(const unsigned int*)(p + (size_t)l * KDIM);
        float br = bf2f((unsigned short)(v & 0xffffu));
        float bi = bf2f((unsigned short)(v >> 16));
        float nzr = fmaf(lam.x, zr, fmaf(-lam.y, zi, br));
        float nzi = fmaf(lam.x, zi, fmaf(lam.y, zr, bi));
        zr = nzr; zi = nzi;
        unsigned int o = (unsigned int)f2bf(nzr) | ((unsigned int)f2bf(nzi) << 16);
        *(unsigned int*)(p + (size_t)l * KDIM) = o;
    }
}

// ---------------------------------------------------------------------------
// Host launch
// ---------------------------------------------------------------------------
extern "C" void kernel_launch(void* const* d_in, const int* in_sizes, int n_in,
                              void* d_out, int out_size, void* d_ws, size_t ws_size,
                              hipStream_t stream) {
    const float* x         = (const float*)d_in[0];
    const float* nu_log    = (const float*)d_in[1];
    const float* theta_log = (const float*)d_in[2];
    const float* B_re      = (const float*)d_in[3];
    const float* B_im      = (const float*)d_in[4];
    const float* C_re      = (const float*)d_in[5];
    const float* C_im      = (const float*)d_in[6];
    const float* Dvec      = (const float*)d_in[7];
    const float* gamma_log = (const float*)d_in[8];
    float* out = (float*)d_out;

    char* ws = (char*)d_ws;
    const size_t BU_BYTES    = (size_t)L_SEQ * KDIM * 2;          // 134 MB bf16
    const size_t XB_BYTES    = (size_t)L_SEQ * HDIM * 2;          // 67 MB bf16
    const size_t W1_BYTES    = (size_t)KDIM * HDIM * 2;           // 256 KB
    const size_t W2_BYTES    = (size_t)HDIM * KDIM * 2;           // 256 KB
    const size_t LAM_BYTES   = (size_t)NSTATE * sizeof(float2);
    const size_t CHUNK_BYTES = (size_t)NCHUNK * NSTATE * sizeof(float2);  // 2 MB

    size_t off = 0;
    unsigned short* Bu  = (unsigned short*)(ws + off); off += BU_BYTES;
    unsigned short* xb  = (unsigned short*)(ws + off); off += XB_BYTES;
    unsigned short* W1  = (unsigned short*)(ws + off); off += W1_BYTES;
    unsigned short* W2  = (unsigned short*)(ws + off); off += W2_BYTES;
    float2* Lambda      = (float2*)(ws + off); off += LAM_BYTES;
    float2* lamLc       = (float2*)(ws + off); off += LAM_BYTES;
    float2* chunk_local = (float2*)(ws + off); off += CHUNK_BYTES;
    float2* chunk_pref  = (float2*)(ws + off); off += CHUNK_BYTES;
    if (ws_size < off) return;

    prep_kernel<<<dim3(256), dim3(256), 0, stream>>>(
        nu_log, theta_log, B_re, B_im, C_re, C_im, gamma_log, W1, W2, Lambda, lamLc);

    castx_kernel<<<dim3((L_SEQ * HDIM) / (256 * 8)), dim3(256), 0, stream>>>(x, xb);

    // GEMM1: (L x 256) * (512 x 256)^T -> Bu (L x 512 bf16, interleaved re/im)
    gemm_mfma<HDIM, KDIM / 128, false>
        <<<dim3(KDIM / 128, L_SEQ / 128), dim3(256), 0, stream>>>(
        xb, W1, KDIM, Bu, nullptr, nullptr, nullptr);

    scan1_kernel<<<dim3(NCHUNK), dim3(NSTATE), 0, stream>>>(Bu, Lambda, chunk_local);
    scan2_kernel<<<dim3(NSTATE), dim3(NCHUNK), 0, stream>>>(chunk_local, lamLc, chunk_pref);
    scan3_kernel<<<dim3(NCHUNK), dim3(NSTATE), 0, stream>>>(Bu, Lambda, chunk_pref);

    // GEMM2: (L x 512) * (256 x 512)^T + D*x -> out (L x 256 fp32)
    gemm_mfma<KDIM, HDIM / 128, true>
        <<<dim3(HDIM / 128, L_SEQ / 128), dim3(256), 0, stream>>>(
        Bu, W2, HDIM, nullptr, out, Dvec, x);
}